// Round 5
// baseline (6533.087 us; speedup 1.0000x reference)
//
#include <hip/hip_runtime.h>
#include <hip/hip_bf16.h>
#include <math.h>

#define B_    64
#define N_    784
#define D_    384
#define CBh   192      // per-branch channels
#define HID_  1536
#define RESO_ 28
#define WIN_  196
#define G_    32       // groups per batch per branch
#define K392  392
#define NW    38416    // WIN_*WIN_
#define CPH   24       // channels per head

// ---------------------------------------------------------------------------
// center_norm (optionally with residual x + alpha*a first).
// block = 128 threads, one row (384 ch) per block; grid.x = chunk rows.
// ---------------------------------------------------------------------------
__global__ void resnorm_kernel(const float* __restrict__ x,
                               const float* __restrict__ abuf,   // nullable
                               const float* __restrict__ alpha,  // nullable
                               const float* __restrict__ gw,
                               const float* __restrict__ gb,
                               float* __restrict__ nout)
{
    const int row = blockIdx.x;
    const int tid = threadIdx.x;
    __shared__ float red[128];
    float vals[3];
    float s = 0.f;
    const size_t base = (size_t)row * D_;
    #pragma unroll
    for (int i = 0; i < 3; ++i) {
        int ch = tid + i * 128;
        float v = x[base + ch];
        if (abuf) v += alpha[ch] * abuf[base + ch];
        vals[i] = v;
        s += v;
    }
    red[tid] = s;
    __syncthreads();
    for (int off = 64; off > 0; off >>= 1) {
        if (tid < off) red[tid] += red[tid + off];
        __syncthreads();
    }
    const float u = red[0] * (1.0f / D_);
    const float scale = (float)D_ / ((float)D_ - 1.0f);
    #pragma unroll
    for (int i = 0; i < 3; ++i) {
        int ch = tid + i * 128;
        nout[base + ch] = gw[ch] * (scale * (vals[i] - u)) + gb[ch];
    }
}

// ---------------------------------------------------------------------------
// compress: wv[b_local, g, k] for both branches, from chunk-local an.
// block = 64 threads per (b_local, n) row; grid.x = CB*N_.
// ---------------------------------------------------------------------------
__global__ void compress_kernel(const float* __restrict__ an,
                                const float* __restrict__ c0w, const float* __restrict__ c0b,
                                const float* __restrict__ c1w, const float* __restrict__ c1b,
                                float* __restrict__ wv0, float* __restrict__ wv1)
{
    const int bn = blockIdx.x;
    const int tid = threadIdx.x;
    const int b = bn / N_, n = bn % N_;
    const int h = n / RESO_, wc = n % RESO_;
    __shared__ float xr[D_];
    for (int i = tid; i < D_; i += 64) xr[i] = an[(size_t)bn * D_ + i];
    __syncthreads();
    if (tid < 32) {
        const int br = tid >> 4;
        const int o  = tid & 15;
        const float* cw  = br ? c1w : c0w;
        const float* cbp = br ? c1b : c0b;
        const float* src = xr + br * CBh;
        float acc = cbp[o];
        for (int ch = 0; ch < CBh; ++ch)
            acc += src[ch] * cw[ch * 16 + o];
        const int mu = o >> 1, dd = o & 1;
        if (br == 0) {
            // branch0: H_sp=28 (n1=1, hs=h), W_sp=7 (n2=4)
            int i2 = wc / 7, wsc = wc % 7;
            int g = i2 * 8 + mu;
            int k = (h * 7 + wsc) * 2 + dd;
            wv0[((size_t)b * G_ + g) * K392 + k] = acc;
        } else {
            // branch1: H_sp=7 (n1=4), W_sp=28 (n2=1, wsc=wc)
            int i1 = h / 7, hs = h % 7;
            int g = i1 * 8 + mu;
            int k = (hs * 28 + wc) * 2 + dd;
            wv1[((size_t)b * G_ + g) * K392 + k] = acc;
        }
    }
}

// ---------------------------------------------------------------------------
// Tiled GEMM with row guards: C(rows x N) = A(rows x K) @ Bw(K x N) + bias.
// BM=BN=64, BK=16, 256 threads, 4x4/thread; grid.y = ceil(rows/64).
// MODE 0: bias store. MODE 2: bias + exact GELU. MODE 3: bias;
// out = resx + a1*resa + a2*val (C may alias resa; own-index only).
// ---------------------------------------------------------------------------
template <int MODE>
__global__ void gemm64_kernel(const float* __restrict__ A, const float* __restrict__ Bw,
                              const float* __restrict__ bias,
                              float* C,
                              int rows, int N, int K,
                              const float* __restrict__ resx,
                              const float* resa,
                              const float* __restrict__ a1,
                              const float* __restrict__ a2)
{
    __shared__ float As[16][64];
    __shared__ float Bs[16][64];
    const int tx = threadIdx.x & 15;
    const int ty = threadIdx.x >> 4;
    const int rowBase = blockIdx.y * 64;
    const int colBase = blockIdx.x * 64;
    float acc[4][4] = {};

    for (int kt = 0; kt < K; kt += 16) {
        #pragma unroll
        for (int i = 0; i < 4; ++i) {
            int e = threadIdx.x * 4 + i;
            int mm = e >> 4, kk = e & 15;
            int gk = kt + kk;
            As[kk][mm] = (rowBase + mm < rows && gk < K)
                       ? A[(size_t)(rowBase + mm) * K + gk] : 0.f;
        }
        #pragma unroll
        for (int i = 0; i < 4; ++i) {
            int e = threadIdx.x * 4 + i;
            int kk = e >> 6, nn = e & 63;
            int gk = kt + kk, gc = colBase + nn;
            Bs[kk][nn] = (gk < K && gc < N) ? Bw[(size_t)gk * N + gc] : 0.f;
        }
        __syncthreads();
        #pragma unroll
        for (int kk = 0; kk < 16; ++kk) {
            float a4[4], b4[4];
            #pragma unroll
            for (int i = 0; i < 4; ++i) a4[i] = As[kk][ty * 4 + i];
            #pragma unroll
            for (int j = 0; j < 4; ++j) b4[j] = Bs[kk][tx * 4 + j];
            #pragma unroll
            for (int i = 0; i < 4; ++i)
                #pragma unroll
                for (int j = 0; j < 4; ++j)
                    acc[i][j] += a4[i] * b4[j];
        }
        __syncthreads();
    }

    #pragma unroll
    for (int i = 0; i < 4; ++i) {
        int gr = rowBase + ty * 4 + i;
        if (gr >= rows) continue;
        #pragma unroll
        for (int j = 0; j < 4; ++j) {
            int gc = colBase + tx * 4 + j;
            if (gc >= N) continue;
            float v = acc[i][j] + bias[gc];
            if (MODE == 2) v = 0.5f * v * (1.0f + erff(v * 0.70710678118654752f));
            if (MODE == 3) {
                size_t idx = (size_t)gr * N + gc;
                v = resx[idx] + a1[gc] * resa[idx] + a2[gc] * v;
            }
            C[(size_t)gr * N + gc] = v;
        }
    }
}

// ---------------------------------------------------------------------------
// softmax (over source axis s) + apply v@p, fused per chunk-local (b,g).
// block = 256 threads (196 active t-columns); grid.x = CB*G_.
// ---------------------------------------------------------------------------
__global__ void softmax_apply_kernel(const float* __restrict__ logits,
                                     const float* __restrict__ an,
                                     float* __restrict__ xcat,
                                     int branch)
{
    const int bg = blockIdx.x;          // chunk-local (b,g)
    const int b = bg >> 5, g = bg & 31;
    const int tid = threadIdx.x;
    const int mu = g & 7, i12 = g >> 3;
    const int choff = branch * CBh + mu * CPH;

    __shared__ float vls[CPH * WIN_];   // v[cc][s]
    for (int idx = tid; idx < CPH * WIN_; idx += 256) {
        int cc = idx / WIN_, s = idx % WIN_;
        int n;
        if (branch == 0) { int hs = s / 7;  int wsc = s % 7;  n = hs * RESO_ + i12 * 7 + wsc; }
        else             { int hs = s / 28; int wsc = s % 28; n = (i12 * 7 + hs) * RESO_ + wsc; }
        vls[idx] = an[((size_t)b * N_ + n) * D_ + choff + cc];
    }
    __syncthreads();

    const int t = tid;
    if (t < WIN_) {
        const float* L = logits + (size_t)bg * NW + t;
        float mx = -1e30f;
        for (int s = 0; s < WIN_; ++s)
            mx = fmaxf(mx, L[(size_t)s * WIN_]);
        float acc[CPH];
        #pragma unroll
        for (int i = 0; i < CPH; ++i) acc[i] = 0.f;
        float sum = 0.f;
        for (int s = 0; s < WIN_; ++s) {
            float e = __expf(L[(size_t)s * WIN_] - mx);
            sum += e;
            #pragma unroll
            for (int cc = 0; cc < CPH; ++cc) acc[cc] += e * vls[cc * WIN_ + s];
        }
        const float inv = 1.0f / sum;
        int nt;
        if (branch == 0) { int hs = t / 7;  int ws2 = t % 7;  nt = hs * RESO_ + i12 * 7 + ws2; }
        else             { int hs = t / 28; int ws2 = t % 28; nt = (i12 * 7 + hs) * RESO_ + ws2; }
        float* dst = xcat + ((size_t)b * N_ + nt) * D_ + choff;
        #pragma unroll
        for (int cc = 0; cc < CPH; ++cc)
            dst[cc] = acc[cc] * inv;
    }
}

// ---------------------------------------------------------------------------
// diagnostic: encode ws_size into out[0] if workspace can't fit CB=1.
// ---------------------------------------------------------------------------
__global__ void diag_kernel(float* out, float v)
{
    if (blockIdx.x == 0 && threadIdx.x == 0) out[0] = v;
}

// ---------------------------------------------------------------------------
extern "C" void kernel_launch(void* const* d_in, const int* in_sizes, int n_in,
                              void* d_out, int out_size, void* d_ws, size_t ws_size,
                              hipStream_t stream)
{
    const float* x     = (const float*)d_in[0];
    const float* n1w   = (const float*)d_in[1];
    const float* n1b   = (const float*)d_in[2];
    const float* n2w   = (const float*)d_in[3];
    const float* n2b   = (const float*)d_in[4];
    const float* c0w   = (const float*)d_in[5];
    const float* c0b   = (const float*)d_in[6];
    const float* g0w   = (const float*)d_in[7];
    const float* g0b   = (const float*)d_in[8];
    const float* c1w   = (const float*)d_in[9];
    const float* c1b   = (const float*)d_in[10];
    const float* g1w   = (const float*)d_in[11];
    const float* g1b   = (const float*)d_in[12];
    const float* projw = (const float*)d_in[13];
    const float* projb = (const float*)d_in[14];
    const float* fc1w  = (const float*)d_in[15];
    const float* fc1b  = (const float*)d_in[16];
    const float* fc2w  = (const float*)d_in[17];
    const float* fc2b  = (const float*)d_in[18];
    const float* al1   = (const float*)d_in[19];
    const float* al2   = (const float*)d_in[20];

    // per-batch scratch (all fp32): bufA + bufB + wv0 + wv1 + region
    // region holds logits (G_*NW) in attention phase, h1 (N_*HID_) in MLP phase.
    const size_t perB = (size_t)N_ * D_ * 4 * 2            // bufA + bufB
                      + (size_t)2 * G_ * K392 * 4          // wv0 + wv1
                      + (size_t)G_ * NW * 4;               // region (>= N_*HID_*4)
    int CB = 0;
    for (int cb = 64; cb >= 1; cb >>= 1) {
        if ((size_t)cb * perB + 8192 <= ws_size) { CB = cb; break; }
    }
    if (CB == 0) {
        diag_kernel<<<1, 64, 0, stream>>>((float*)d_out, 1024.0f + (float)(ws_size >> 10));
        return;
    }

    char* w = (char*)d_ws;
    size_t off = 0;
    auto alloc = [&](size_t bytes) { char* p = w + off; off += (bytes + 255) & ~(size_t)255; return p; };
    float* bufA   = (float*)alloc((size_t)CB * N_ * D_ * 4);     // an -> mn
    float* bufB   = (float*)alloc((size_t)CB * N_ * D_ * 4);     // xcat
    float* wv0    = (float*)alloc((size_t)CB * G_ * K392 * 4);
    float* wv1    = (float*)alloc((size_t)CB * G_ * K392 * 4);
    float* region = (float*)alloc((size_t)CB * G_ * NW * 4);     // logits -> h1

    float* an     = bufA;
    float* mn     = bufA;     // overwrites an after attention phase
    float* xcat   = bufB;
    float* logits = region;
    float* h1     = region;   // fc1 output (logits dead after softmax-apply)

    const int rowsC = CB * N_;
    const int bgC   = CB * G_;

    for (int b0 = 0; b0 < B_; b0 += CB) {
        const float* xc   = x + (size_t)b0 * N_ * D_;
        float*       outc = (float*)d_out + (size_t)b0 * N_ * D_;
        float*       accA = outc;   // proj output parked in d_out

        // 1) norm1 -> an
        resnorm_kernel<<<rowsC, 128, 0, stream>>>(xc, nullptr, nullptr, n1w, n1b, an);
        // 2) compress -> wv (both branches)
        compress_kernel<<<rowsC, 64, 0, stream>>>(an, c0w, c0b, c1w, c1b, wv0, wv1);
        // 3/4) per branch: generate GEMM -> logits; softmax+apply -> xcat
        for (int branch = 0; branch < 2; ++branch) {
            const float* wv = branch ? wv1 : wv0;
            const float* gw = branch ? g1w : g0w;
            const float* gb = branch ? g1b : g0b;
            dim3 grid((NW + 63) / 64, (bgC + 63) / 64);
            gemm64_kernel<0><<<grid, 256, 0, stream>>>(
                wv, gw, gb, logits, bgC, NW, K392, nullptr, nullptr, nullptr, nullptr);
            softmax_apply_kernel<<<bgC, 256, 0, stream>>>(logits, an, xcat, branch);
        }
        // 5) proj -> accA (in d_out)
        {
            dim3 grid((D_ + 63) / 64, (rowsC + 63) / 64);
            gemm64_kernel<0><<<grid, 256, 0, stream>>>(
                xcat, projw, projb, accA, rowsC, D_, D_, nullptr, nullptr, nullptr, nullptr);
        }
        // 6) mn = center_norm(x + alpha1*accA)  (overwrites an)
        resnorm_kernel<<<rowsC, 128, 0, stream>>>(xc, accA, al1, n2w, n2b, mn);
        // 7) fc1 + GELU -> h1 (overwrites logits region)
        {
            dim3 grid((HID_ + 63) / 64, (rowsC + 63) / 64);
            gemm64_kernel<2><<<grid, 256, 0, stream>>>(
                mn, fc1w, fc1b, h1, rowsC, HID_, D_, nullptr, nullptr, nullptr, nullptr);
        }
        // 8) fc2: out = x + alpha1*accA + alpha2*(h1@fc2w + fc2b)  (in place over accA)
        {
            dim3 grid((D_ + 63) / 64, (rowsC + 63) / 64);
            gemm64_kernel<3><<<grid, 256, 0, stream>>>(
                h1, fc2w, fc2b, outc, rowsC, D_, HID_, xc, accA, al1, al2);
        }
    }
    (void)in_sizes; (void)n_in; (void)out_size;
}

// Round 6
// 1909.958 us; speedup vs baseline: 3.4205x; 3.4205x over previous
//
#include <hip/hip_runtime.h>
#include <hip/hip_bf16.h>
#include <math.h>

typedef __hip_bfloat16 bf16;
typedef short short8 __attribute__((ext_vector_type(8)));
typedef float f32x4 __attribute__((ext_vector_type(4)));

#define B_    64
#define N_    784
#define D_    384
#define CBh   192      // per-branch channels
#define HID_  1536
#define RESO_ 28
#define WIN_  196
#define G_    32       // groups per batch per branch
#define K392  392
#define KP416 416      // K392 padded to multiple of 32
#define NW    38416    // WIN_*WIN_
#define CPH   24       // channels per head

static __device__ __forceinline__ float toF(float v) { return v; }
static __device__ __forceinline__ float toF(bf16 v)  { return __bfloat162float(v); }
template <typename T> static __device__ __forceinline__ T fromF(float v);
template <> __device__ __forceinline__ float fromF<float>(float v) { return v; }
template <> __device__ __forceinline__ bf16  fromF<bf16>(float v)  { return __float2bfloat16(v); }

// ---------------------------------------------------------------------------
// center_norm (optionally with residual x + alpha*a first). fp32 in, T out.
// block = 128 threads, one row (384 ch) per block; grid.x = chunk rows.
// ---------------------------------------------------------------------------
template <typename TO>
__global__ void resnorm_kernel(const float* __restrict__ x,
                               const float* __restrict__ abuf,   // nullable
                               const float* __restrict__ alpha,  // nullable
                               const float* __restrict__ gw,
                               const float* __restrict__ gb,
                               TO* __restrict__ nout)
{
    const int row = blockIdx.x;
    const int tid = threadIdx.x;
    __shared__ float red[128];
    float vals[3];
    float s = 0.f;
    const size_t base = (size_t)row * D_;
    #pragma unroll
    for (int i = 0; i < 3; ++i) {
        int ch = tid + i * 128;
        float v = x[base + ch];
        if (abuf) v += alpha[ch] * abuf[base + ch];
        vals[i] = v;
        s += v;
    }
    red[tid] = s;
    __syncthreads();
    for (int off = 64; off > 0; off >>= 1) {
        if (tid < off) red[tid] += red[tid + off];
        __syncthreads();
    }
    const float u = red[0] * (1.0f / D_);
    const float scale = (float)D_ / ((float)D_ - 1.0f);
    #pragma unroll
    for (int i = 0; i < 3; ++i) {
        int ch = tid + i * 128;
        nout[base + ch] = fromF<TO>(gw[ch] * (scale * (vals[i] - u)) + gb[ch]);
    }
}

// ---------------------------------------------------------------------------
// compress: wv[b_local, g, k] for both branches, from chunk-local an.
// block = 64 threads per (b_local, n) row; grid.x = CB*N_. kstride = row
// stride of wv (KP416 for MFMA path, K392 for fallback).
// ---------------------------------------------------------------------------
template <typename TI, typename TO>
__global__ void compress_kernel(const TI* __restrict__ an,
                                const float* __restrict__ c0w, const float* __restrict__ c0b,
                                const float* __restrict__ c1w, const float* __restrict__ c1b,
                                TO* __restrict__ wv0, TO* __restrict__ wv1, int kstride)
{
    const int bn = blockIdx.x;
    const int tid = threadIdx.x;
    const int b = bn / N_, n = bn % N_;
    const int h = n / RESO_, wc = n % RESO_;
    __shared__ float xr[D_];
    for (int i = tid; i < D_; i += 64) xr[i] = toF(an[(size_t)bn * D_ + i]);
    __syncthreads();
    if (tid < 32) {
        const int br = tid >> 4;
        const int o  = tid & 15;
        const float* cw  = br ? c1w : c0w;
        const float* cbp = br ? c1b : c0b;
        const float* src = xr + br * CBh;
        float acc = cbp[o];
        for (int ch = 0; ch < CBh; ++ch)
            acc += src[ch] * cw[ch * 16 + o];
        const int mu = o >> 1, dd = o & 1;
        if (br == 0) {
            // branch0: H_sp=28 (n1=1, hs=h), W_sp=7 (n2=4)
            int i2 = wc / 7, wsc = wc % 7;
            int g = i2 * 8 + mu;
            int k = (h * 7 + wsc) * 2 + dd;
            wv0[((size_t)b * G_ + g) * kstride + k] = fromF<TO>(acc);
        } else {
            // branch1: H_sp=7 (n1=4), W_sp=28 (n2=1, wsc=wc)
            int i1 = h / 7, hs = h % 7;
            int g = i1 * 8 + mu;
            int k = (hs * 28 + wc) * 2 + dd;
            wv1[((size_t)b * G_ + g) * kstride + k] = fromF<TO>(acc);
        }
    }
}

// zero the K-pad columns [K392, KP416) of wv
__global__ void pad_zero_kernel(bf16* __restrict__ wv, int rows)
{
    int i = blockIdx.x * 256 + threadIdx.x;
    if (i < rows * (KP416 - K392)) {
        int r = i / (KP416 - K392), k = i % (KP416 - K392);
        wv[(size_t)r * KP416 + K392 + k] = __float2bfloat16(0.f);
    }
}

// ---------------------------------------------------------------------------
// weight convert + transpose: src fp32 [K][N] -> dst bf16 [N][Kp], zero pad.
// block 256 (32x8), grid (ceil(N/32), ceil(Kp/32)).
// ---------------------------------------------------------------------------
__global__ void transpose_conv_kernel(const float* __restrict__ src, bf16* __restrict__ dst,
                                      int K, int N, int Kp)
{
    __shared__ float t[32][33];
    const int tx = threadIdx.x & 31;
    const int ty = threadIdx.x >> 5;   // 0..7
    const int kb = blockIdx.y * 32, nb = blockIdx.x * 32;
    for (int r = ty; r < 32; r += 8) {
        int k = kb + r, n = nb + tx;
        t[r][tx] = (k < K && n < N) ? src[(size_t)k * N + n] : 0.f;
    }
    __syncthreads();
    for (int r = ty; r < 32; r += 8) {
        int n = nb + r, kk = kb + tx;
        if (n < N && kk < Kp) dst[(size_t)n * Kp + kk] = __float2bfloat16(t[tx][r]);
    }
}

// ---------------------------------------------------------------------------
// MFMA GEMM: C(rows x N) = A(rows x Kp bf16) @ Bt(N x Kp bf16)^T + bias.
// 128x128 tile, 256 thr = 4 waves (2x2 of 64x64), mfma_f32_16x16x32_bf16,
// 4x4 16x16-fragments per wave, fp32 accum. Row/col guards everywhere.
// MODE 0: bias, fp32 store. MODE 2: bias+GELU, bf16 store.
// MODE 3: bias; out = resx + a1*resa + a2*val, fp32 store (C may alias resa).
// ---------------------------------------------------------------------------
template <int MODE>
__global__ __launch_bounds__(256)
void mfma_gemm_kernel(const bf16* __restrict__ A, const bf16* __restrict__ Bt,
                      const float* __restrict__ bias, void* Cv,
                      int rows, int N, int Kp,
                      const float* __restrict__ resx, const float* resa,
                      const float* __restrict__ a1, const float* __restrict__ a2)
{
    __shared__ short As[128 * 40];   // stride 40 elems (80B): 16B-aligned, 2-way banks
    __shared__ short Bs[128 * 40];
    const int tid  = threadIdx.x;
    const int lane = tid & 63;
    const int wave = tid >> 6;
    const int wm   = (wave >> 1) * 64;
    const int wn   = (wave & 1) * 64;
    const int quad = lane >> 4;
    const int l16  = lane & 15;
    const int rowBase = blockIdx.y * 128;
    const int colBase = blockIdx.x * 128;

    f32x4 acc[4][4] = {};

    for (int kt = 0; kt < Kp; kt += 32) {
        #pragma unroll
        for (int i = 0; i < 2; ++i) {
            int s = tid * 2 + i;               // 0..511
            int m = s >> 2, ks = (s & 3) * 8;
            uint4 v = make_uint4(0u, 0u, 0u, 0u);
            if (rowBase + m < rows)
                v = *reinterpret_cast<const uint4*>(A + (size_t)(rowBase + m) * Kp + kt + ks);
            *reinterpret_cast<uint4*>(&As[m * 40 + ks]) = v;
        }
        #pragma unroll
        for (int i = 0; i < 2; ++i) {
            int s = tid * 2 + i;
            int n = s >> 2, ks = (s & 3) * 8;
            uint4 v = make_uint4(0u, 0u, 0u, 0u);
            if (colBase + n < N)
                v = *reinterpret_cast<const uint4*>(Bt + (size_t)(colBase + n) * Kp + kt + ks);
            *reinterpret_cast<uint4*>(&Bs[n * 40 + ks]) = v;
        }
        __syncthreads();
        short8 af[4], bg[4];
        #pragma unroll
        for (int i = 0; i < 4; ++i)
            af[i] = *reinterpret_cast<const short8*>(&As[(wm + i * 16 + l16) * 40 + quad * 8]);
        #pragma unroll
        for (int j = 0; j < 4; ++j)
            bg[j] = *reinterpret_cast<const short8*>(&Bs[(wn + j * 16 + l16) * 40 + quad * 8]);
        #pragma unroll
        for (int i = 0; i < 4; ++i)
            #pragma unroll
            for (int j = 0; j < 4; ++j)
                acc[i][j] = __builtin_amdgcn_mfma_f32_16x16x32_bf16(af[i], bg[j], acc[i][j], 0, 0, 0);
        __syncthreads();
    }

    // epilogue: C/D layout col = lane&15, row = quad*4 + reg  [m89/m91]
    #pragma unroll
    for (int i = 0; i < 4; ++i) {
        #pragma unroll
        for (int j = 0; j < 4; ++j) {
            int col = colBase + wn + j * 16 + l16;
            if (col >= N) continue;
            #pragma unroll
            for (int r = 0; r < 4; ++r) {
                int row = rowBase + wm + i * 16 + quad * 4 + r;
                if (row >= rows) continue;
                float v = acc[i][j][r] + bias[col];
                if (MODE == 2) v = 0.5f * v * (1.0f + erff(v * 0.70710678118654752f));
                if (MODE == 3) {
                    size_t idx = (size_t)row * N + col;
                    v = resx[idx] + a1[col] * resa[idx] + a2[col] * v;
                }
                if (MODE == 2) ((bf16*)Cv)[(size_t)row * N + col] = __float2bfloat16(v);
                else           ((float*)Cv)[(size_t)row * N + col] = v;
            }
        }
    }
}

// ---------------------------------------------------------------------------
// FALLBACK fp32 tiled GEMM (round-5, known good). Used only if ws too small.
// ---------------------------------------------------------------------------
template <int MODE>
__global__ void gemm64_kernel(const float* __restrict__ A, const float* __restrict__ Bw,
                              const float* __restrict__ bias,
                              float* C,
                              int rows, int N, int K,
                              const float* __restrict__ resx,
                              const float* resa,
                              const float* __restrict__ a1,
                              const float* __restrict__ a2)
{
    __shared__ float As[16][64];
    __shared__ float Bs[16][64];
    const int tx = threadIdx.x & 15;
    const int ty = threadIdx.x >> 4;
    const int rowBase = blockIdx.y * 64;
    const int colBase = blockIdx.x * 64;
    float acc[4][4] = {};

    for (int kt = 0; kt < K; kt += 16) {
        #pragma unroll
        for (int i = 0; i < 4; ++i) {
            int e = threadIdx.x * 4 + i;
            int mm = e >> 4, kk = e & 15;
            int gk = kt + kk;
            As[kk][mm] = (rowBase + mm < rows && gk < K)
                       ? A[(size_t)(rowBase + mm) * K + gk] : 0.f;
        }
        #pragma unroll
        for (int i = 0; i < 4; ++i) {
            int e = threadIdx.x * 4 + i;
            int kk = e >> 6, nn = e & 63;
            int gk = kt + kk, gc = colBase + nn;
            Bs[kk][nn] = (gk < K && gc < N) ? Bw[(size_t)gk * N + gc] : 0.f;
        }
        __syncthreads();
        #pragma unroll
        for (int kk = 0; kk < 16; ++kk) {
            float a4[4], b4[4];
            #pragma unroll
            for (int i = 0; i < 4; ++i) a4[i] = As[kk][ty * 4 + i];
            #pragma unroll
            for (int j = 0; j < 4; ++j) b4[j] = Bs[kk][tx * 4 + j];
            #pragma unroll
            for (int i = 0; i < 4; ++i)
                #pragma unroll
                for (int j = 0; j < 4; ++j)
                    acc[i][j] += a4[i] * b4[j];
        }
        __syncthreads();
    }

    #pragma unroll
    for (int i = 0; i < 4; ++i) {
        int gr = rowBase + ty * 4 + i;
        if (gr >= rows) continue;
        #pragma unroll
        for (int j = 0; j < 4; ++j) {
            int gc = colBase + tx * 4 + j;
            if (gc >= N) continue;
            float v = acc[i][j] + bias[gc];
            if (MODE == 2) v = 0.5f * v * (1.0f + erff(v * 0.70710678118654752f));
            if (MODE == 3) {
                size_t idx = (size_t)gr * N + gc;
                v = resx[idx] + a1[gc] * resa[idx] + a2[gc] * v;
            }
            C[(size_t)gr * N + gc] = v;
        }
    }
}

// ---------------------------------------------------------------------------
// softmax (over source axis s) + apply v@p, fused per chunk-local (b,g).
// logits fp32; an / xcat of type T. block=256; grid.x = CB*G_.
// ---------------------------------------------------------------------------
template <typename T>
__global__ void softmax_apply_kernel(const float* __restrict__ logits,
                                     const T* __restrict__ an,
                                     T* __restrict__ xcat,
                                     int branch)
{
    const int bg = blockIdx.x;
    const int b = bg >> 5, g = bg & 31;
    const int tid = threadIdx.x;
    const int mu = g & 7, i12 = g >> 3;
    const int choff = branch * CBh + mu * CPH;

    __shared__ float vls[CPH * WIN_];   // v[cc][s]
    for (int idx = tid; idx < CPH * WIN_; idx += 256) {
        int cc = idx / WIN_, s = idx % WIN_;
        int n;
        if (branch == 0) { int hs = s / 7;  int wsc = s % 7;  n = hs * RESO_ + i12 * 7 + wsc; }
        else             { int hs = s / 28; int wsc = s % 28; n = (i12 * 7 + hs) * RESO_ + wsc; }
        vls[idx] = toF(an[((size_t)b * N_ + n) * D_ + choff + cc]);
    }
    __syncthreads();

    const int t = tid;
    if (t < WIN_) {
        const float* L = logits + (size_t)bg * NW + t;
        float mx = -1e30f;
        for (int s = 0; s < WIN_; ++s)
            mx = fmaxf(mx, L[(size_t)s * WIN_]);
        float acc[CPH];
        #pragma unroll
        for (int i = 0; i < CPH; ++i) acc[i] = 0.f;
        float sum = 0.f;
        for (int s = 0; s < WIN_; ++s) {
            float e = __expf(L[(size_t)s * WIN_] - mx);
            sum += e;
            #pragma unroll
            for (int cc = 0; cc < CPH; ++cc) acc[cc] += e * vls[cc * WIN_ + s];
        }
        const float inv = 1.0f / sum;
        int nt;
        if (branch == 0) { int hs = t / 7;  int ws2 = t % 7;  nt = hs * RESO_ + i12 * 7 + ws2; }
        else             { int hs = t / 28; int ws2 = t % 28; nt = (i12 * 7 + hs) * RESO_ + ws2; }
        T* dst = xcat + ((size_t)b * N_ + nt) * D_ + choff;
        #pragma unroll
        for (int cc = 0; cc < CPH; ++cc)
            dst[cc] = fromF<T>(acc[cc] * inv);
    }
}

__global__ void diag_kernel(float* out, float v)
{
    if (blockIdx.x == 0 && threadIdx.x == 0) out[0] = v;
}

// ---------------------------------------------------------------------------
extern "C" void kernel_launch(void* const* d_in, const int* in_sizes, int n_in,
                              void* d_out, int out_size, void* d_ws, size_t ws_size,
                              hipStream_t stream)
{
    const float* x     = (const float*)d_in[0];
    const float* n1w   = (const float*)d_in[1];
    const float* n1b   = (const float*)d_in[2];
    const float* n2w   = (const float*)d_in[3];
    const float* n2b   = (const float*)d_in[4];
    const float* c0w   = (const float*)d_in[5];
    const float* c0b   = (const float*)d_in[6];
    const float* g0w   = (const float*)d_in[7];
    const float* g0b   = (const float*)d_in[8];
    const float* c1w   = (const float*)d_in[9];
    const float* c1b   = (const float*)d_in[10];
    const float* g1w   = (const float*)d_in[11];
    const float* g1b   = (const float*)d_in[12];
    const float* projw = (const float*)d_in[13];
    const float* projb = (const float*)d_in[14];
    const float* fc1w  = (const float*)d_in[15];
    const float* fc1b  = (const float*)d_in[16];
    const float* fc2w  = (const float*)d_in[17];
    const float* fc2b  = (const float*)d_in[18];
    const float* al1   = (const float*)d_in[19];
    const float* al2   = (const float*)d_in[20];

    char* w = (char*)d_ws;
    size_t off = 0;
    auto alloc = [&](size_t bytes) { char* p = w + off; off += (bytes + 255) & ~(size_t)255; return p; };

    // ======== MFMA path sizing ========
    const size_t fixedB = ((size_t)NW * KP416 * 2) * 2      // g0t + g1t
                        + (size_t)D_ * D_ * 2               // projt [384][384]
                        + (size_t)HID_ * D_ * 2             // fc1t  [1536][384]
                        + (size_t)D_ * HID_ * 2             // fc2t  [384][1536]
                        + 4096;
    const size_t perB_m = (size_t)N_ * D_ * 2 * 2           // bufA + bufB (bf16)
                        + (size_t)2 * G_ * KP416 * 2        // wv0 + wv1 (bf16)
                        + (size_t)G_ * NW * 4;              // region: logits fp32 (>= h1 bf16)
    int CBm = 0;
    for (int cb = 64; cb >= 1; cb >>= 1)
        if (fixedB + (size_t)cb * perB_m + 8192 <= ws_size) { CBm = cb; break; }

    if (CBm > 0) {
        // ---------------- MFMA path ----------------
        bf16* g0t   = (bf16*)alloc((size_t)NW * KP416 * 2);
        bf16* g1t   = (bf16*)alloc((size_t)NW * KP416 * 2);
        bf16* projt = (bf16*)alloc((size_t)D_ * D_ * 2);
        bf16* fc1t  = (bf16*)alloc((size_t)HID_ * D_ * 2);
        bf16* fc2t  = (bf16*)alloc((size_t)D_ * HID_ * 2);
        const int CB = CBm;
        bf16*  bufA   = (bf16*)alloc((size_t)CB * N_ * D_ * 2);
        bf16*  bufB   = (bf16*)alloc((size_t)CB * N_ * D_ * 2);
        bf16*  wv0    = (bf16*)alloc((size_t)CB * G_ * KP416 * 2);
        bf16*  wv1    = (bf16*)alloc((size_t)CB * G_ * KP416 * 2);
        char*  region = alloc((size_t)CB * G_ * NW * 4);

        bf16*  an     = bufA;
        bf16*  mn     = bufA;
        bf16*  xcat   = bufB;
        float* logits = (float*)region;
        bf16*  h1     = (bf16*)region;

        // one-time weight transposes (bf16 B^T layout)
        transpose_conv_kernel<<<dim3((NW + 31) / 32, KP416 / 32), 256, 0, stream>>>(g0w, g0t, K392, NW, KP416);
        transpose_conv_kernel<<<dim3((NW + 31) / 32, KP416 / 32), 256, 0, stream>>>(g1w, g1t, K392, NW, KP416);
        transpose_conv_kernel<<<dim3(D_ / 32, D_ / 32),   256, 0, stream>>>(projw, projt, D_, D_, D_);
        transpose_conv_kernel<<<dim3(HID_ / 32, D_ / 32), 256, 0, stream>>>(fc1w, fc1t, D_, HID_, D_);
        transpose_conv_kernel<<<dim3(D_ / 32, HID_ / 32), 256, 0, stream>>>(fc2w, fc2t, HID_, D_, HID_);

        const int rowsC = CB * N_;
        const int bgC   = CB * G_;

        for (int b0 = 0; b0 < B_; b0 += CB) {
            const float* xc   = x + (size_t)b0 * N_ * D_;
            float*       outc = (float*)d_out + (size_t)b0 * N_ * D_;
            float*       accA = outc;

            resnorm_kernel<bf16><<<rowsC, 128, 0, stream>>>(xc, nullptr, nullptr, n1w, n1b, an);
            compress_kernel<bf16, bf16><<<rowsC, 64, 0, stream>>>(an, c0w, c0b, c1w, c1b, wv0, wv1, KP416);
            pad_zero_kernel<<<(bgC * (KP416 - K392) + 255) / 256, 256, 0, stream>>>(wv0, bgC);
            pad_zero_kernel<<<(bgC * (KP416 - K392) + 255) / 256, 256, 0, stream>>>(wv1, bgC);

            for (int branch = 0; branch < 2; ++branch) {
                const bf16*  wv = branch ? wv1 : wv0;
                const bf16*  gt = branch ? g1t : g0t;
                const float* gb = branch ? g1b : g0b;
                dim3 grid((NW + 127) / 128, (bgC + 127) / 128);
                mfma_gemm_kernel<0><<<grid, 256, 0, stream>>>(
                    wv, gt, gb, logits, bgC, NW, KP416, nullptr, nullptr, nullptr, nullptr);
                softmax_apply_kernel<bf16><<<bgC, 256, 0, stream>>>(logits, an, xcat, branch);
            }
            {
                dim3 grid((D_ + 127) / 128, (rowsC + 127) / 128);
                mfma_gemm_kernel<0><<<grid, 256, 0, stream>>>(
                    xcat, projt, projb, accA, rowsC, D_, D_, nullptr, nullptr, nullptr, nullptr);
            }
            resnorm_kernel<bf16><<<rowsC, 128, 0, stream>>>(xc, accA, al1, n2w, n2b, mn);
            {
                dim3 grid((HID_ + 127) / 128, (rowsC + 127) / 128);
                mfma_gemm_kernel<2><<<grid, 256, 0, stream>>>(
                    mn, fc1t, fc1b, h1, rowsC, HID_, D_, nullptr, nullptr, nullptr, nullptr);
            }
            {
                dim3 grid((D_ + 127) / 128, (rowsC + 127) / 128);
                mfma_gemm_kernel<3><<<grid, 256, 0, stream>>>(
                    h1, fc2t, fc2b, outc, rowsC, D_, HID_, xc, accA, al1, al2);
            }
        }
        (void)in_sizes; (void)n_in; (void)out_size;
        return;
    }

    // ======== fallback fp32 path (round-5, known good) ========
    const size_t perB = (size_t)N_ * D_ * 4 * 2
                      + (size_t)2 * G_ * K392 * 4
                      + (size_t)G_ * NW * 4;
    int CB = 0;
    for (int cb = 64; cb >= 1; cb >>= 1)
        if ((size_t)cb * perB + 8192 <= ws_size) { CB = cb; break; }
    if (CB == 0) {
        diag_kernel<<<1, 64, 0, stream>>>((float*)d_out, 1024.0f + (float)(ws_size >> 10));
        return;
    }

    float* bufA   = (float*)alloc((size_t)CB * N_ * D_ * 4);
    float* bufB   = (float*)alloc((size_t)CB * N_ * D_ * 4);
    float* wv0    = (float*)alloc((size_t)CB * G_ * K392 * 4);
    float* wv1    = (float*)alloc((size_t)CB * G_ * K392 * 4);
    float* region = (float*)alloc((size_t)CB * G_ * NW * 4);

    float* an     = bufA;
    float* mn     = bufA;
    float* xcat   = bufB;
    float* logits = region;
    float* h1     = region;

    const int rowsC = CB * N_;
    const int bgC   = CB * G_;

    for (int b0 = 0; b0 < B_; b0 += CB) {
        const float* xc   = x + (size_t)b0 * N_ * D_;
        float*       outc = (float*)d_out + (size_t)b0 * N_ * D_;
        float*       accA = outc;

        resnorm_kernel<float><<<rowsC, 128, 0, stream>>>(xc, nullptr, nullptr, n1w, n1b, an);
        compress_kernel<float, float><<<rowsC, 64, 0, stream>>>(an, c0w, c0b, c1w, c1b, wv0, wv1, K392);
        for (int branch = 0; branch < 2; ++branch) {
            const float* wv = branch ? wv1 : wv0;
            const float* gw = branch ? g1w : g0w;
            const float* gb = branch ? g1b : g0b;
            dim3 grid((NW + 63) / 64, (bgC + 63) / 64);
            gemm64_kernel<0><<<grid, 256, 0, stream>>>(
                wv, gw, gb, logits, bgC, NW, K392, nullptr, nullptr, nullptr, nullptr);
            softmax_apply_kernel<float><<<bgC, 256, 0, stream>>>(logits, an, xcat, branch);
        }
        {
            dim3 grid((D_ + 63) / 64, (rowsC + 63) / 64);
            gemm64_kernel<0><<<grid, 256, 0, stream>>>(
                xcat, projw, projb, accA, rowsC, D_, D_, nullptr, nullptr, nullptr, nullptr);
        }
        resnorm_kernel<float><<<rowsC, 128, 0, stream>>>(xc, accA, al1, n2w, n2b, mn);
        {
            dim3 grid((HID_ + 63) / 64, (rowsC + 63) / 64);
            gemm64_kernel<2><<<grid, 256, 0, stream>>>(
                mn, fc1w, fc1b, h1, rowsC, HID_, D_, nullptr, nullptr, nullptr, nullptr);
        }
        {
            dim3 grid((D_ + 63) / 64, (rowsC + 63) / 64);
            gemm64_kernel<3><<<grid, 256, 0, stream>>>(
                h1, fc2w, fc2b, outc, rowsC, D_, HID_, xc, accA, al1, al2);
        }
    }
    (void)in_sizes; (void)n_in; (void)out_size;
}